// Round 1
// baseline (7292.009 us; speedup 1.0000x reference)
//
#include <hip/hip_runtime.h>
#include <hip/hip_bf16.h>

#define NPAD 16640
#define TOK  16385
#define CDIM 512
#define NHEAD 8
#define DHEAD 64
#define NLAND 256
#define LFAC  65
#define PAD0  255
#define NCHUNK 64
#define CHUNKK 260   // NPAD / NCHUNK

__device__ __forceinline__ float wave_sum(float v){
  #pragma unroll
  for(int o=32;o;o>>=1) v += __shfl_xor(v,o);
  return v;
}
__device__ __forceinline__ float wave_max(float v){
  #pragma unroll
  for(int o=32;o;o>>=1) v = fmaxf(v, __shfl_xor(v,o));
  return v;
}

// ---------------- cls token ----------------
__global__ void k_set_cls(float* A, const float* __restrict__ cls){
  int t = threadIdx.x;
  if(t < CDIM) A[t] = cls[t];
}

// ---------------- layernorm + front pad ----------------
// one wave per padded row; rows < PAD0 are zeros
__global__ __launch_bounds__(256) void k_ln_pad(const float* __restrict__ A,
    const float* __restrict__ g, const float* __restrict__ b, float* __restrict__ B){
  int w = threadIdx.x >> 6, lane = threadIdx.x & 63;
  int row = blockIdx.x*4 + w;
  float* out = B + (size_t)row*CDIM;
  if(row < PAD0){
    #pragma unroll
    for(int i=0;i<8;i++) out[lane + i*64] = 0.f;
    return;
  }
  const float* x = A + (size_t)(row-PAD0)*CDIM;
  int c0 = lane*4, c1 = 256 + lane*4;
  float4 v0 = *(const float4*)(x + c0);
  float4 v1 = *(const float4*)(x + c1);
  float xs[8] = {v0.x,v0.y,v0.z,v0.w,v1.x,v1.y,v1.z,v1.w};
  float s = 0;
  #pragma unroll
  for(int i=0;i<8;i++) s += xs[i];
  s = wave_sum(s);
  float mu = s * (1.f/512.f);
  float vs = 0;
  #pragma unroll
  for(int i=0;i<8;i++){ float d = xs[i]-mu; vs += d*d; }
  vs = wave_sum(vs) * (1.f/512.f);
  float rs = rsqrtf(vs + 1e-5f);
  float4 g0 = *(const float4*)(g + c0); float4 g1 = *(const float4*)(g + c1);
  float4 b0 = *(const float4*)(b + c0); float4 b1 = *(const float4*)(b + c1);
  float4 o0, o1;
  o0.x = (xs[0]-mu)*rs*g0.x + b0.x; o0.y = (xs[1]-mu)*rs*g0.y + b0.y;
  o0.z = (xs[2]-mu)*rs*g0.z + b0.z; o0.w = (xs[3]-mu)*rs*g0.w + b0.w;
  o1.x = (xs[4]-mu)*rs*g1.x + b1.x; o1.y = (xs[5]-mu)*rs*g1.y + b1.y;
  o1.z = (xs[6]-mu)*rs*g1.z + b1.z; o1.w = (xs[7]-mu)*rs*g1.w + b1.w;
  *(float4*)(out + c0) = o0;
  *(float4*)(out + c1) = o1;
}

// ---------------- big GEMM: 128x64 tile, BK=16, thread 8x4 ----------------
// MODE 0: fc1  out0[m*512+n] = relu(acc + bias[n])
// MODE 1: qkv  scatter to q/k/v head-major, q scaled 0.125
// MODE 2: proj out0[m*512+n] += acc + bias[n]
template<int MODE>
__global__ __launch_bounds__(256) void k_gemm(const float* __restrict__ A, int lda,
    const float* __restrict__ W, int ldw, const float* __restrict__ bias,
    float* out0, float* out1, float* out2, int M, int K){
  __shared__ float As[16][128];
  __shared__ float Ws[16][64];
  int t = threadIdx.x;
  int tx = t & 15, ty = t >> 4;
  int row0 = blockIdx.y * 128, n0 = blockIdx.x * 64;
  float acc[8][4] = {};
  for(int k0 = 0; k0 < K; k0 += 16){
    #pragma unroll
    for(int r=0;r<2;r++){
      int idx = t + r*256;
      int ar = idx >> 2, kq = (idx & 3) * 4;
      float4 v = make_float4(0.f,0.f,0.f,0.f);
      int gr = row0 + ar;
      if(gr < M) v = *(const float4*)(A + (size_t)gr*lda + k0 + kq);
      As[kq+0][ar] = v.x; As[kq+1][ar] = v.y; As[kq+2][ar] = v.z; As[kq+3][ar] = v.w;
    }
    {
      int kr = t >> 4, nq = (t & 15) * 4;
      float4 v = *(const float4*)(W + (size_t)(k0+kr)*ldw + n0 + nq);
      *(float4*)&Ws[kr][nq] = v;
    }
    __syncthreads();
    #pragma unroll
    for(int k=0;k<16;k++){
      float bv[4];
      #pragma unroll
      for(int j=0;j<4;j++) bv[j] = Ws[k][tx*4+j];
      #pragma unroll
      for(int i=0;i<8;i++){
        float av = As[k][ty*8+i];
        #pragma unroll
        for(int j=0;j<4;j++) acc[i][j] += av * bv[j];
      }
    }
    __syncthreads();
  }
  #pragma unroll
  for(int i=0;i<8;i++){
    int gm = row0 + ty*8 + i;
    if(gm >= M) continue;
    #pragma unroll
    for(int j=0;j<4;j++){
      int gn = n0 + tx*4 + j;
      float v = acc[i][j];
      if(MODE == 0){
        v += bias[gn];
        out0[(size_t)gm*CDIM + gn] = v > 0.f ? v : 0.f;
      } else if(MODE == 1){
        int p = gn >> 9, r = gn & 511;
        int hh = r >> 6, dd = r & 63;
        if(p == 0) v *= 0.125f;
        float* dst = (p==0) ? out0 : (p==1 ? out1 : out2);
        dst[((size_t)hh*NPAD + gm)*DHEAD + dd] = v;
      } else {
        out0[(size_t)gm*CDIM + gn] += v + bias[gn];
      }
    }
  }
}

// ---------------- landmark means ----------------
__global__ void k_landmark(const float* __restrict__ src, float* __restrict__ dst){
  int bidx = blockIdx.x;               // h*256 + m
  int h = bidx >> 8, m = bidx & 255, d = threadIdx.x;
  const float* p = src + ((size_t)h*NPAD + (size_t)m*LFAC)*DHEAD + d;
  float s = 0;
  for(int j=0;j<LFAC;j++) s += p[(size_t)j*DHEAD];
  dst[(size_t)bidx*DHEAD + d] = s * (1.f/LFAC);
}

// ---------------- a2 = softmax(ql @ kl^T) ----------------
__global__ __launch_bounds__(256) void k_a2(const float* __restrict__ ql,
    const float* __restrict__ kl, float* __restrict__ a2){
  __shared__ __hip_bfloat16 klt[64*256];  // [d][m]
  int h = blockIdx.y;
  int t = threadIdx.x;
  const float* klh = kl + (size_t)h*NLAND*DHEAD;
  for(int r=0;r<64;r++){
    int idx = r*256 + t;
    int d = idx >> 8, m = idx & 255;
    klt[idx] = __float2bfloat16(klh[m*DHEAD + d]);
  }
  __syncthreads();
  int w = t >> 6, lane = t & 63;
  const float* qlh = ql + (size_t)h*NLAND*DHEAD;
  for(int rr=0; rr<16; rr++){
    int m = blockIdx.x*64 + w*16 + rr;
    const float* q = qlh + (size_t)m*DHEAD;
    float s[4] = {0,0,0,0};
    #pragma unroll
    for(int d=0; d<64; d++){
      float qv = q[d];
      #pragma unroll
      for(int qd=0; qd<4; qd++)
        s[qd] += qv * __bfloat162float(klt[d*256 + qd*64 + lane]);
    }
    float e[4], den = 0.f;
    #pragma unroll
    for(int qd=0; qd<4; qd++){ e[qd] = __expf(s[qd]); den += e[qd]; }
    den = wave_sum(den);
    float inv = 1.f/den;
    float* arow = a2 + ((size_t)h*NLAND + m)*NLAND;
    #pragma unroll
    for(int qd=0; qd<4; qd++) arow[qd*64 + lane] = e[qd]*inv;
  }
}

// ---------------- pinv init: col-sum max, global max, z0 = a2^T / s ----------------
__global__ void k_colmax(const float* __restrict__ a2, float* __restrict__ hmax){
  __shared__ float red[4];
  int h = blockIdx.x, t = threadIdx.x;
  const float* p = a2 + (size_t)h*65536 + t;
  float s = 0;
  for(int m=0;m<256;m++) s += p[(size_t)m*256];
  float mx = wave_max(s);
  if((t & 63) == 0) red[t>>6] = mx;
  __syncthreads();
  if(t == 0) hmax[h] = fmaxf(fmaxf(red[0],red[1]), fmaxf(red[2],red[3]));
}
__global__ void k_scal(const float* __restrict__ hmax, float* __restrict__ scal){
  int t = threadIdx.x;
  float v = (t < 8) ? hmax[t] : -1e30f;
  v = wave_max(v);
  if(t == 0) scal[0] = v;   // row-sum max of a softmax matrix == 1
}
__global__ void k_zinit(const float* __restrict__ a2, const float* __restrict__ scal,
                        float* __restrict__ z){
  int h = blockIdx.y;
  int idx = blockIdx.x*256 + threadIdx.x;   // 0..65535
  int m = idx >> 8, j = idx & 255;
  z[(size_t)h*65536 + idx] = a2[(size_t)h*65536 + (size_t)j*256 + m] / scal[0];
}
__global__ void k_eIminus(const float* __restrict__ X, float* __restrict__ T, float alpha){
  int idx = blockIdx.x*256 + threadIdx.x;   // 8*65536 total
  int loc = idx & 65535;
  int r = loc >> 8, c = loc & 255;
  T[idx] = ((r==c) ? alpha : 0.f) - X[idx];
}

// ---------------- small batched GEMM (pinv / w2): 32x32 tiles ----------------
// MODE 0: C = acc ; MODE 1: C = alpha*I - acc ; MODE 2: C = alpha*acc
template<int MODE>
__global__ __launch_bounds__(256) void k_sgemm(const float* __restrict__ A,
    const float* __restrict__ B, float* __restrict__ C,
    int M, int N, int K, long sA, long sB, long sC, float alpha){
  __shared__ float As[32][33];
  __shared__ float Bs[32][33];
  int bh = blockIdx.z;
  const float* Ah = A + (size_t)bh*sA;
  const float* Bh = B + (size_t)bh*sB;
  float* Ch = C + (size_t)bh*sC;
  int m0 = blockIdx.y*32, n0 = blockIdx.x*32;
  int t = threadIdx.x, tx = t & 15, ty = t >> 4;
  float acc[2][2] = {};
  for(int k0=0; k0<K; k0+=32){
    int ar = t >> 3, ac = (t & 7) * 4;
    float4 va = *(const float4*)(Ah + (size_t)(m0+ar)*K + k0 + ac);
    *(float4*)&As[ar][ac] = va;
    float4 vb = *(const float4*)(Bh + (size_t)(k0+ar)*N + n0 + ac);
    *(float4*)&Bs[ar][ac] = vb;
    __syncthreads();
    #pragma unroll
    for(int k=0;k<32;k++){
      float a0 = As[ty*2][k], a1 = As[ty*2+1][k];
      float b0 = Bs[k][tx*2], b1 = Bs[k][tx*2+1];
      acc[0][0] += a0*b0; acc[0][1] += a0*b1;
      acc[1][0] += a1*b0; acc[1][1] += a1*b1;
    }
    __syncthreads();
  }
  #pragma unroll
  for(int i=0;i<2;i++){
    #pragma unroll
    for(int j=0;j<2;j++){
      int gm = m0 + ty*2 + i, gn = n0 + tx*2 + j;
      float v = acc[i][j];
      if(MODE == 1) v = ((gm==gn) ? alpha : 0.f) - v;
      if(MODE == 2) v = alpha * v;
      Ch[(size_t)gm*N + gn] = v;
    }
  }
}

// ---------------- a3 @ v streaming (chunked, no-max softmax) ----------------
__global__ __launch_bounds__(256) void k_a3v(const float* __restrict__ ql,
    const float* __restrict__ Kb, const float* __restrict__ Vb,
    float* __restrict__ numP, float* __restrict__ denP){
  __shared__ __hip_bfloat16 qlt[64*256];  // [d][m]
  __shared__ float kr[64], vr[64];
  int h = blockIdx.x, c = blockIdx.y;
  int t = threadIdx.x;
  const float* qlh = ql + (size_t)h*NLAND*DHEAD;
  for(int r=0;r<64;r++){
    int idx = r*256 + t;
    int d = idx >> 8, m = idx & 255;
    qlt[idx] = __float2bfloat16(qlh[m*DHEAD + d]);
  }
  __syncthreads();
  int g = t >> 6, d = t & 63;
  float accv[64];
  #pragma unroll
  for(int i=0;i<64;i++) accv[i] = 0.f;
  float den = 0.f;
  const float* Kh = Kb + (size_t)h*NPAD*DHEAD;
  const float* Vh = Vb + (size_t)h*NPAD*DHEAD;
  int nbeg = c*CHUNKK;
  for(int n = nbeg; n < nbeg + CHUNKK; n++){
    if(t < 64) kr[t] = Kh[(size_t)n*DHEAD + t];
    else if(t < 128) vr[t-64] = Vh[(size_t)n*DHEAD + (t-64)];
    __syncthreads();
    float s = 0.f;
    #pragma unroll
    for(int dd=0; dd<64; dd++) s += __bfloat162float(qlt[dd*256 + t]) * kr[dd];
    float e = __expf(s);
    den += e;
    float vv = vr[d];
    #pragma unroll
    for(int i=0;i<64;i++){
      float ei = __shfl(e, i);
      accv[i] += ei * vv;
    }
    __syncthreads();
  }
  denP[((size_t)h*NCHUNK + c)*NLAND + t] = den;
  float* np = numP + (((size_t)h*NCHUNK + c)*NLAND + g*64)*DHEAD + d;
  #pragma unroll
  for(int i=0;i<64;i++) np[(size_t)i*DHEAD] = accv[i];
}

__global__ void k_a3v_comb(const float* __restrict__ numP, const float* __restrict__ denP,
                           float* __restrict__ a3v){
  int bidx = blockIdx.x;           // h*256 + m
  int h = bidx >> 8, m = bidx & 255;
  int d = threadIdx.x;
  float s = 0.f, den = 0.f;
  for(int c=0;c<NCHUNK;c++){
    s += numP[(((size_t)h*NCHUNK + c)*NLAND + m)*DHEAD + d];
    den += denP[((size_t)h*NCHUNK + c)*NLAND + m];
  }
  a3v[((size_t)h*NLAND + m)*DHEAD + d] = s / den;
}

// ---------------- out = softmax(q @ kl^T) @ w2  (writes F pre-proj) ----------------
__global__ __launch_bounds__(256) void k_a1(const float* __restrict__ Qb,
    const float* __restrict__ kl, const float* __restrict__ w2, float* __restrict__ F){
  __shared__ __hip_bfloat16 klt[64*256];   // [d][m]
  __shared__ __hip_bfloat16 w2s[256*64];   // [m][d]
  int h = blockIdx.x, cb = blockIdx.y;
  int t = threadIdx.x;
  const float* klh = kl + (size_t)h*NLAND*DHEAD;
  const float* w2h = w2 + (size_t)h*NLAND*DHEAD;
  for(int r=0;r<64;r++){
    int idx = r*256 + t;
    int d = idx >> 8, m = idx & 255;
    klt[idx] = __float2bfloat16(klh[m*DHEAD + d]);
    w2s[idx] = __float2bfloat16(w2h[idx]);
  }
  __syncthreads();
  int g = t >> 6, lane = t & 63;
  const float* Qh = Qb + (size_t)h*NPAD*DHEAD;
  for(int rr=0; rr<32; rr++){
    int n = cb*128 + g*32 + rr;
    const float* q = Qh + (size_t)n*DHEAD;
    float s[4] = {0,0,0,0};
    #pragma unroll
    for(int d=0; d<64; d++){
      float qv = q[d];
      #pragma unroll
      for(int qd=0; qd<4; qd++)
        s[qd] += qv * __bfloat162float(klt[d*256 + qd*64 + lane]);
    }
    float e[4], den = 0.f;
    #pragma unroll
    for(int qd=0; qd<4; qd++){ e[qd] = __expf(s[qd]); den += e[qd]; }
    den = wave_sum(den);
    float inv = 1.f/den;
    #pragma unroll
    for(int qd=0; qd<4; qd++) e[qd] *= inv;
    float acc = 0.f;
    #pragma unroll
    for(int i=0;i<64;i++){
      #pragma unroll
      for(int qd=0; qd<4; qd++){
        float p = __shfl(e[qd], i);
        acc += p * __bfloat162float(w2s[(qd*64 + i)*64 + lane]);
      }
    }
    F[(size_t)n*CDIM + h*DHEAD + lane] = acc;
  }
}

// ---------------- residual depthwise conv along sequence (k=33) ----------------
__global__ void k_resconv(const float* __restrict__ Vb, const float* __restrict__ rw,
                          float* __restrict__ F){
  int n = blockIdx.x;
  int c = blockIdx.y*256 + threadIdx.x;
  int h = c >> 6, d = c & 63;
  const float* vh = Vb + (size_t)h*NPAD*DHEAD + d;
  float s = 0.f;
  #pragma unroll
  for(int j=0;j<33;j++){
    int nn = n + j - 16;
    if(nn >= 0 && nn < NPAD) s += rw[h*33 + j] * vh[(size_t)nn*DHEAD];
  }
  F[(size_t)n*CDIM + c] += s;
}

// ---------------- transpose (R x C) -> (C x R) ----------------
__global__ void k_transpose(const float* __restrict__ in, float* __restrict__ out,
                            int R, int C){
  __shared__ float tile[32][33];
  int r0 = blockIdx.x*32, c0 = blockIdx.y*32;
  int tx = threadIdx.x, ty = threadIdx.y;
  #pragma unroll
  for(int r=0;r<4;r++) tile[ty + r*8][tx] = in[(size_t)(r0 + ty + r*8)*C + c0 + tx];
  __syncthreads();
  #pragma unroll
  for(int r=0;r<4;r++) out[(size_t)(c0 + ty + r*8)*R + r0 + tx] = tile[tx][ty + r*8];
}

// ---------------- PPEG depthwise 7/5/3 conv on 128x128 image ----------------
__global__ __launch_bounds__(256) void k_ppeg(const float* __restrict__ img,
    const float* __restrict__ w7, const float* __restrict__ b7,
    const float* __restrict__ w5, const float* __restrict__ b5,
    const float* __restrict__ w3, const float* __restrict__ b3,
    float* __restrict__ out){
  __shared__ float patch[22*22];
  __shared__ float wbuf[83];
  int c = blockIdx.y;
  int tj = blockIdx.x & 7, ti = blockIdx.x >> 3;
  int t = threadIdx.x;
  const float* im = img + (size_t)c*16384;
  int i0 = ti*16 - 3, j0 = tj*16 - 3;
  for(int idx = t; idx < 484; idx += 256){
    int pi = idx / 22, pj = idx % 22;
    int gi = i0 + pi, gj = j0 + pj;
    patch[idx] = (gi>=0 && gi<128 && gj>=0 && gj<128) ? im[gi*128 + gj] : 0.f;
  }
  if(t < 49) wbuf[t] = w7[c*49 + t];
  else if(t < 74) wbuf[t] = w5[c*25 + (t-49)];
  else if(t < 83) wbuf[t] = w3[c*9 + (t-74)];
  __syncthreads();
  int i = t >> 4, j = t & 15;
  float s = patch[(i+3)*22 + (j+3)];
  #pragma unroll
  for(int a=0;a<7;a++)
    #pragma unroll
    for(int bq=0;bq<7;bq++) s += wbuf[a*7+bq] * patch[(i+a)*22 + (j+bq)];
  s += b7[c];
  #pragma unroll
  for(int a=0;a<5;a++)
    #pragma unroll
    for(int bq=0;bq<5;bq++) s += wbuf[49+a*5+bq] * patch[(i+a+1)*22 + (j+bq+1)];
  s += b5[c];
  #pragma unroll
  for(int a=0;a<3;a++)
    #pragma unroll
    for(int bq=0;bq<3;bq++) s += wbuf[74+a*3+bq] * patch[(i+a+2)*22 + (j+bq+2)];
  s += b3[c];
  out[(size_t)c*16384 + (ti*16+i)*128 + (tj*16+j)] = s;
}

// ---------------- final LN(row0) + fc2 ----------------
__global__ __launch_bounds__(512) void k_final(const float* __restrict__ A,
    const float* __restrict__ g, const float* __restrict__ b,
    const float* __restrict__ w, const float* __restrict__ bias,
    float* __restrict__ outp){
  __shared__ float red[8];
  int t = threadIdx.x, wv = t >> 6;
  float x = A[t];
  float s = wave_sum(x);
  if((t & 63) == 0) red[wv] = s;
  __syncthreads();
  float mu = 0;
  #pragma unroll
  for(int i=0;i<8;i++) mu += red[i];
  mu *= (1.f/512.f);
  __syncthreads();
  float dx = x - mu;
  s = wave_sum(dx*dx);
  if((t & 63) == 0) red[wv] = s;
  __syncthreads();
  float var = 0;
  #pragma unroll
  for(int i=0;i<8;i++) var += red[i];
  var *= (1.f/512.f);
  float xn = dx * rsqrtf(var + 1e-5f) * g[t] + b[t];
  __syncthreads();
  for(int o=0;o<4;o++){
    s = wave_sum(xn * w[t*4 + o]);
    if((t & 63) == 0) red[wv] = s;
    __syncthreads();
    if(t == 0){
      float r = 0;
      #pragma unroll
      for(int i=0;i<8;i++) r += red[i];
      outp[o] = r + bias[o];
    }
    __syncthreads();
  }
}

extern "C" void kernel_launch(void* const* d_in, const int* in_sizes, int n_in,
                              void* d_out, int out_size, void* d_ws, size_t ws_size,
                              hipStream_t stream) {
  (void)in_sizes; (void)n_in; (void)out_size; (void)ws_size;
  const float* data_x = (const float*)d_in[0];
  const float* fc1_w  = (const float*)d_in[1];
  const float* fc1_b  = (const float*)d_in[2];
  const float* cls_tk = (const float*)d_in[3];
  const float* ng[2]  = {(const float*)d_in[4],  (const float*)d_in[16]};
  const float* nb[2]  = {(const float*)d_in[5],  (const float*)d_in[17]};
  const float* qkvw[2]= {(const float*)d_in[6],  (const float*)d_in[18]};
  const float* outw[2]= {(const float*)d_in[7],  (const float*)d_in[19]};
  const float* outb[2]= {(const float*)d_in[8],  (const float*)d_in[20]};
  const float* resw[2]= {(const float*)d_in[9],  (const float*)d_in[21]};
  const float* w7 = (const float*)d_in[10]; const float* pb7 = (const float*)d_in[11];
  const float* w5 = (const float*)d_in[12]; const float* pb5 = (const float*)d_in[13];
  const float* w3 = (const float*)d_in[14]; const float* pb3 = (const float*)d_in[15];
  const float* norm_g = (const float*)d_in[22];
  const float* norm_b = (const float*)d_in[23];
  const float* fc2_w  = (const float*)d_in[24];
  const float* fc2_b  = (const float*)d_in[25];

  float* ws = (float*)d_ws;
  float* Ab   = ws;                         // 16385*512
  float* Bb   = Ab + (size_t)TOK*CDIM;      // 16640*512
  float* Qb   = Bb + (size_t)NPAD*CDIM;
  float* Kb   = Qb + (size_t)NPAD*CDIM;
  float* Vb   = Kb + (size_t)NPAD*CDIM;
  float* Fb   = Vb + (size_t)NPAD*CDIM;     // pre-proj out; also a3v numP scratch
  float* qlb  = Fb + (size_t)NPAD*CDIM;     // 8*256*64
  float* klb  = qlb + NHEAD*NLAND*DHEAD;
  float* a2b  = klb + NHEAD*NLAND*DHEAD;    // 8*256*256
  float* z0b  = a2b + NHEAD*NLAND*NLAND;
  float* z1b  = z0b + NHEAD*NLAND*NLAND;
  float* Xb_  = z1b + NHEAD*NLAND*NLAND;
  float* Tb_  = Xb_ + NHEAD*NLAND*NLAND;
  float* Ub_  = Tb_ + NHEAD*NLAND*NLAND;
  float* a3vb = Ub_ + NHEAD*NLAND*NLAND;    // 8*256*64
  float* w2b  = a3vb + NHEAD*NLAND*DHEAD;
  float* denP = w2b + NHEAD*NLAND*DHEAD;    // 8*64*256
  float* hmax = denP + NHEAD*NCHUNK*NLAND;  // 8
  float* scal = hmax + 8;                   // 1

  k_set_cls<<<1, 512, 0, stream>>>(Ab, cls_tk);
  // fc1: 16384 x 1024 x 512, relu+bias, into Ab rows 1..16384
  k_gemm<0><<<dim3(8, 128), 256, 0, stream>>>(data_x, 1024, fc1_w, 512, fc1_b,
                                              Ab + CDIM, nullptr, nullptr, 16384, 1024);
  for(int L=0; L<2; L++){
    k_ln_pad<<<NPAD/4, 256, 0, stream>>>(Ab, ng[L], nb[L], Bb);
    k_gemm<1><<<dim3(24, 130), 256, 0, stream>>>(Bb, CDIM, qkvw[L], 1536, nullptr,
                                                 Qb, Kb, Vb, NPAD, CDIM);
    k_landmark<<<NHEAD*NLAND, 64, 0, stream>>>(Qb, qlb);
    k_landmark<<<NHEAD*NLAND, 64, 0, stream>>>(Kb, klb);
    k_a2<<<dim3(4, NHEAD), 256, 0, stream>>>(qlb, klb, a2b);
    k_colmax<<<NHEAD, 256, 0, stream>>>(a2b, hmax);
    k_scal<<<1, 64, 0, stream>>>(hmax, scal);
    k_zinit<<<dim3(256, NHEAD), 256, 0, stream>>>(a2b, scal, z0b);
    float* zc = z0b; float* zn = z1b;
    for(int it=0; it<6; it++){
      k_sgemm<0><<<dim3(8,8,NHEAD), 256, 0, stream>>>(a2b, zc, Xb_, 256,256,256,
                                                      65536,65536,65536, 0.f);
      k_eIminus<<<NHEAD*65536/256, 256, 0, stream>>>(Xb_, Tb_, 7.f);
      k_sgemm<1><<<dim3(8,8,NHEAD), 256, 0, stream>>>(Xb_, Tb_, Ub_, 256,256,256,
                                                      65536,65536,65536, 15.f);
      k_sgemm<1><<<dim3(8,8,NHEAD), 256, 0, stream>>>(Xb_, Ub_, Tb_, 256,256,256,
                                                      65536,65536,65536, 13.f);
      k_sgemm<2><<<dim3(8,8,NHEAD), 256, 0, stream>>>(zc, Tb_, zn, 256,256,256,
                                                      65536,65536,65536, 0.25f);
      float* tmp = zc; zc = zn; zn = tmp;
    }
    k_a3v<<<dim3(NHEAD, NCHUNK), 256, 0, stream>>>(qlb, Kb, Vb, Fb, denP);
    k_a3v_comb<<<NHEAD*NLAND, 64, 0, stream>>>(Fb, denP, a3vb);
    k_sgemm<0><<<dim3(2,8,NHEAD), 256, 0, stream>>>(zc, a3vb, w2b, 256,64,256,
                                                    65536,16384,16384, 0.f);
    k_a1<<<dim3(NHEAD, 130), 256, 0, stream>>>(Qb, klb, w2b, Fb);
    k_resconv<<<dim3(NPAD, 2), 256, 0, stream>>>(Vb, resw[L], Fb);
    k_gemm<2><<<dim3(8, 129), 256, 0, stream>>>(Fb + (size_t)PAD0*CDIM, CDIM,
                                                outw[L], CDIM, outb[L],
                                                Ab, nullptr, nullptr, TOK, CDIM);
    if(L == 0){
      k_transpose<<<dim3(512, 16), dim3(32,8), 0, stream>>>(Ab + CDIM, Bb, 16384, 512);
      k_ppeg<<<dim3(64, 512), 256, 0, stream>>>(Bb, w7, pb7, w5, pb5, w3, pb3, Qb);
      k_transpose<<<dim3(16, 512), dim3(32,8), 0, stream>>>(Qb, Ab + CDIM, 512, 16384);
    }
  }
  k_final<<<1, 512, 0, stream>>>(Ab, norm_g, norm_b, fc2_w, fc2_b, (float*)d_out);
}

// Round 2
// 4064.711 us; speedup vs baseline: 1.7940x; 1.7940x over previous
//
#include <hip/hip_runtime.h>
#include <hip/hip_bf16.h>

#define NPAD 16640
#define TOK  16385
#define CDIM 512
#define NHEAD 8
#define DHEAD 64
#define NLAND 256
#define LFAC  65
#define PAD0  255
#define NCHUNK 65   // chunks of 256 rows: 65*256 = 16640

__device__ __forceinline__ float wave_sum(float v){
  #pragma unroll
  for(int o=32;o;o>>=1) v += __shfl_xor(v,o);
  return v;
}
__device__ __forceinline__ float wave_max(float v){
  #pragma unroll
  for(int o=32;o;o>>=1) v = fmaxf(v, __shfl_xor(v,o));
  return v;
}

// bf16 pack/unpack helpers (RNE pack; unpack via bit ops, 1 VALU op each)
__device__ __forceinline__ unsigned bfbits(float x){
  unsigned u = __float_as_uint(x);
  return (u + 0x7fffu + ((u >> 16) & 1u)) >> 16;
}
__device__ __forceinline__ unsigned packbf(float a, float b){
  return bfbits(a) | (bfbits(b) << 16);
}
__device__ __forceinline__ float lo_bf(unsigned u){ return __uint_as_float(u << 16); }
__device__ __forceinline__ float hi_bf(unsigned u){ return __uint_as_float(u & 0xffff0000u); }

// ---------------- cls token ----------------
__global__ void k_set_cls(float* A, const float* __restrict__ cls){
  int t = threadIdx.x;
  if(t < CDIM) A[t] = cls[t];
}

// ---------------- layernorm + front pad ----------------
__global__ __launch_bounds__(256) void k_ln_pad(const float* __restrict__ A,
    const float* __restrict__ g, const float* __restrict__ b, float* __restrict__ B){
  int w = threadIdx.x >> 6, lane = threadIdx.x & 63;
  int row = blockIdx.x*4 + w;
  float* out = B + (size_t)row*CDIM;
  if(row < PAD0){
    #pragma unroll
    for(int i=0;i<8;i++) out[lane + i*64] = 0.f;
    return;
  }
  const float* x = A + (size_t)(row-PAD0)*CDIM;
  int c0 = lane*4, c1 = 256 + lane*4;
  float4 v0 = *(const float4*)(x + c0);
  float4 v1 = *(const float4*)(x + c1);
  float xs[8] = {v0.x,v0.y,v0.z,v0.w,v1.x,v1.y,v1.z,v1.w};
  float s = 0;
  #pragma unroll
  for(int i=0;i<8;i++) s += xs[i];
  s = wave_sum(s);
  float mu = s * (1.f/512.f);
  float vs = 0;
  #pragma unroll
  for(int i=0;i<8;i++){ float d = xs[i]-mu; vs += d*d; }
  vs = wave_sum(vs) * (1.f/512.f);
  float rs = rsqrtf(vs + 1e-5f);
  float4 g0 = *(const float4*)(g + c0); float4 g1 = *(const float4*)(g + c1);
  float4 b0 = *(const float4*)(b + c0); float4 b1 = *(const float4*)(b + c1);
  float4 o0, o1;
  o0.x = (xs[0]-mu)*rs*g0.x + b0.x; o0.y = (xs[1]-mu)*rs*g0.y + b0.y;
  o0.z = (xs[2]-mu)*rs*g0.z + b0.z; o0.w = (xs[3]-mu)*rs*g0.w + b0.w;
  o1.x = (xs[4]-mu)*rs*g1.x + b1.x; o1.y = (xs[5]-mu)*rs*g1.y + b1.y;
  o1.z = (xs[6]-mu)*rs*g1.z + b1.z; o1.w = (xs[7]-mu)*rs*g1.w + b1.w;
  *(float4*)(out + c0) = o0;
  *(float4*)(out + c1) = o1;
}

// ---------------- big GEMM: 128x128 tile, BK=16, thread 8x8 ----------------
// MODE 0: fc1  relu(acc+bias) ; MODE 1: qkv scatter head-major, q*0.125 ; MODE 2: proj +=
template<int MODE>
__global__ __launch_bounds__(256) void k_gemm(const float* __restrict__ A, int lda,
    const float* __restrict__ W, int ldw, const float* __restrict__ bias,
    float* out0, float* out1, float* out2, int M, int K){
  __shared__ float As[16][128];
  __shared__ float Ws[16][132];
  int t = threadIdx.x;
  int tx = t & 15, ty = t >> 4;
  int row0 = blockIdx.y * 128, n0 = blockIdx.x * 128;
  float acc[8][8] = {};
  for(int k0 = 0; k0 < K; k0 += 16){
    #pragma unroll
    for(int r=0;r<2;r++){
      int idx = t + r*256;
      int ar = idx >> 2, kq = (idx & 3) * 4;
      float4 v = make_float4(0.f,0.f,0.f,0.f);
      int gr = row0 + ar;
      if(gr < M) v = *(const float4*)(A + (size_t)gr*lda + k0 + kq);
      As[kq+0][ar] = v.x; As[kq+1][ar] = v.y; As[kq+2][ar] = v.z; As[kq+3][ar] = v.w;
    }
    #pragma unroll
    for(int r=0;r<2;r++){
      int idx = t + r*256;
      int kr = idx >> 5, nq = (idx & 31) * 4;
      float4 v = *(const float4*)(W + (size_t)(k0+kr)*ldw + n0 + nq);
      *(float4*)&Ws[kr][nq] = v;
    }
    __syncthreads();
    #pragma unroll
    for(int k=0;k<16;k++){
      float a[8], b[8];
      *(float4*)&a[0] = *(const float4*)&As[k][ty*8];
      *(float4*)&a[4] = *(const float4*)&As[k][ty*8+4];
      *(float4*)&b[0] = *(const float4*)&Ws[k][tx*8];
      *(float4*)&b[4] = *(const float4*)&Ws[k][tx*8+4];
      #pragma unroll
      for(int i=0;i<8;i++)
        #pragma unroll
        for(int j=0;j<8;j++) acc[i][j] += a[i]*b[j];
    }
    __syncthreads();
  }
  #pragma unroll
  for(int i=0;i<8;i++){
    int gm = row0 + ty*8 + i;
    if(gm >= M) continue;
    #pragma unroll
    for(int j=0;j<8;j++){
      int gn = n0 + tx*8 + j;
      float v = acc[i][j];
      if(MODE == 0){
        v += bias[gn];
        out0[(size_t)gm*CDIM + gn] = v > 0.f ? v : 0.f;
      } else if(MODE == 1){
        int p = gn >> 9, r = gn & 511;
        int hh = r >> 6, dd = r & 63;
        if(p == 0) v *= 0.125f;
        float* dst = (p==0) ? out0 : (p==1 ? out1 : out2);
        dst[((size_t)hh*NPAD + gm)*DHEAD + dd] = v;
      } else {
        out0[(size_t)gm*CDIM + gn] += v + bias[gn];
      }
    }
  }
}

// ---------------- landmark means ----------------
__global__ void k_landmark(const float* __restrict__ src, float* __restrict__ dst){
  int bidx = blockIdx.x;               // h*256 + m
  int h = bidx >> 8, m = bidx & 255, d = threadIdx.x;
  const float* p = src + ((size_t)h*NPAD + (size_t)m*LFAC)*DHEAD + d;
  float s = 0;
  for(int j=0;j<LFAC;j++) s += p[(size_t)j*DHEAD];
  dst[(size_t)bidx*DHEAD + d] = s * (1.f/LFAC);
}

// ---------------- a2 = softmax(ql @ kl^T) ----------------
__global__ __launch_bounds__(256) void k_a2(const float* __restrict__ ql,
    const float* __restrict__ kl, float* __restrict__ a2){
  __shared__ __hip_bfloat16 klt[64*256];  // [d][m]
  int h = blockIdx.y;
  int t = threadIdx.x;
  const float* klh = kl + (size_t)h*NLAND*DHEAD;
  for(int r=0;r<64;r++){
    int idx = r*256 + t;
    int d = idx >> 8, m = idx & 255;
    klt[idx] = __float2bfloat16(klh[m*DHEAD + d]);
  }
  __syncthreads();
  int w = t >> 6, lane = t & 63;
  const float* qlh = ql + (size_t)h*NLAND*DHEAD;
  for(int rr=0; rr<16; rr++){
    int m = blockIdx.x*64 + w*16 + rr;
    const float* q = qlh + (size_t)m*DHEAD;
    float s[4] = {0,0,0,0};
    #pragma unroll
    for(int d=0; d<64; d++){
      float qv = q[d];
      #pragma unroll
      for(int qd=0; qd<4; qd++)
        s[qd] += qv * __bfloat162float(klt[d*256 + qd*64 + lane]);
    }
    float e[4], den = 0.f;
    #pragma unroll
    for(int qd=0; qd<4; qd++){ e[qd] = __expf(s[qd]); den += e[qd]; }
    den = wave_sum(den);
    float inv = 1.f/den;
    float* arow = a2 + ((size_t)h*NLAND + m)*NLAND;
    #pragma unroll
    for(int qd=0; qd<4; qd++) arow[qd*64 + lane] = e[qd]*inv;
  }
}

// ---------------- pinv init ----------------
__global__ void k_colmax(const float* __restrict__ a2, float* __restrict__ hmax){
  __shared__ float red[4];
  int h = blockIdx.x, t = threadIdx.x;
  const float* p = a2 + (size_t)h*65536 + t;
  float s = 0;
  for(int m=0;m<256;m++) s += p[(size_t)m*256];
  float mx = wave_max(s);
  if((t & 63) == 0) red[t>>6] = mx;
  __syncthreads();
  if(t == 0) hmax[h] = fmaxf(fmaxf(red[0],red[1]), fmaxf(red[2],red[3]));
}
__global__ void k_scal(const float* __restrict__ hmax, float* __restrict__ scal){
  int t = threadIdx.x;
  float v = (t < 8) ? hmax[t] : -1e30f;
  v = wave_max(v);
  if(t == 0) scal[0] = v;
}
__global__ void k_zinit(const float* __restrict__ a2, const float* __restrict__ scal,
                        float* __restrict__ z){
  int h = blockIdx.y;
  int idx = blockIdx.x*256 + threadIdx.x;
  int m = idx >> 8, j = idx & 255;
  z[(size_t)h*65536 + idx] = a2[(size_t)h*65536 + (size_t)j*256 + m] / scal[0];
}
__global__ void k_eIminus(const float* __restrict__ X, float* __restrict__ T, float alpha){
  int idx = blockIdx.x*256 + threadIdx.x;
  int loc = idx & 65535;
  int r = loc >> 8, c = loc & 255;
  T[idx] = ((r==c) ? alpha : 0.f) - X[idx];
}

// ---------------- small batched GEMM (pinv / w2): 32x32 tiles ----------------
template<int MODE>
__global__ __launch_bounds__(256) void k_sgemm(const float* __restrict__ A,
    const float* __restrict__ B, float* __restrict__ C,
    int M, int N, int K, long sA, long sB, long sC, float alpha){
  __shared__ float As[32][33];
  __shared__ float Bs[32][33];
  int bh = blockIdx.z;
  const float* Ah = A + (size_t)bh*sA;
  const float* Bh = B + (size_t)bh*sB;
  float* Ch = C + (size_t)bh*sC;
  int m0 = blockIdx.y*32, n0 = blockIdx.x*32;
  int t = threadIdx.x, tx = t & 15, ty = t >> 4;
  float acc[2][2] = {};
  for(int k0=0; k0<K; k0+=32){
    int ar = t >> 3, ac = (t & 7) * 4;
    float4 va = *(const float4*)(Ah + (size_t)(m0+ar)*K + k0 + ac);
    *(float4*)&As[ar][ac] = va;
    float4 vb = *(const float4*)(Bh + (size_t)(k0+ar)*N + n0 + ac);
    *(float4*)&Bs[ar][ac] = vb;
    __syncthreads();
    #pragma unroll
    for(int k=0;k<32;k++){
      float a0 = As[ty*2][k], a1 = As[ty*2+1][k];
      float b0 = Bs[k][tx*2], b1 = Bs[k][tx*2+1];
      acc[0][0] += a0*b0; acc[0][1] += a0*b1;
      acc[1][0] += a1*b0; acc[1][1] += a1*b1;
    }
    __syncthreads();
  }
  #pragma unroll
  for(int i=0;i<2;i++){
    #pragma unroll
    for(int j=0;j<2;j++){
      int gm = m0 + ty*2 + i, gn = n0 + tx*2 + j;
      float v = acc[i][j];
      if(MODE == 1) v = ((gm==gn) ? alpha : 0.f) - v;
      if(MODE == 2) v = alpha * v;
      Ch[(size_t)gm*N + gn] = v;
    }
  }
}

// ---------------- a3@v: per-thread-row streaming, bf16 LDS broadcast ----------------
// block = (head h, chunk c). 256 threads = 256 ql rows; m in [c*256, c*256+256).
__global__ __launch_bounds__(256) void k_a3v(const float* __restrict__ ql,
    const float* __restrict__ Kb, const float* __restrict__ Vb,
    float* __restrict__ numP, float* __restrict__ denP){
  __shared__ unsigned kL[256*32];
  __shared__ unsigned vL[256*32];
  int h = blockIdx.x, c = blockIdx.y, t = threadIdx.x;
  const float* Kh = Kb + ((size_t)h*NPAD + (size_t)c*256)*DHEAD;
  const float* Vh = Vb + ((size_t)h*NPAD + (size_t)c*256)*DHEAD;
  #pragma unroll
  for(int i=0;i<16;i++){
    int fi = i*256 + t;
    float4 a = *(const float4*)(Kh + (size_t)fi*4);
    float4 b = *(const float4*)(Vh + (size_t)fi*4);
    kL[fi*2]   = packbf(a.x,a.y); kL[fi*2+1] = packbf(a.z,a.w);
    vL[fi*2]   = packbf(b.x,b.y); vL[fi*2+1] = packbf(b.z,b.w);
  }
  __syncthreads();
  const float* qp = ql + ((size_t)h*NLAND + t)*DHEAD;
  float q[64];
  #pragma unroll
  for(int i=0;i<16;i++){
    float4 v = *(const float4*)(qp + i*4);
    q[i*4]=v.x; q[i*4+1]=v.y; q[i*4+2]=v.z; q[i*4+3]=v.w;
  }
  float out[64];
  #pragma unroll
  for(int i=0;i<64;i++) out[i] = 0.f;
  float den = 0.f;
  for(int m=0;m<256;m++){
    const uint4* kr = (const uint4*)&kL[m*32];
    float s0=0,s1=0,s2=0,s3=0;
    #pragma unroll
    for(int i=0;i<8;i++){
      uint4 u = kr[i];
      s0 += q[i*8+0]*lo_bf(u.x) + q[i*8+1]*hi_bf(u.x);
      s1 += q[i*8+2]*lo_bf(u.y) + q[i*8+3]*hi_bf(u.y);
      s2 += q[i*8+4]*lo_bf(u.z) + q[i*8+5]*hi_bf(u.z);
      s3 += q[i*8+6]*lo_bf(u.w) + q[i*8+7]*hi_bf(u.w);
    }
    float e = __expf((s0+s1)+(s2+s3));
    den += e;
    const uint4* vr = (const uint4*)&vL[m*32];
    #pragma unroll
    for(int i=0;i<8;i++){
      uint4 u = vr[i];
      out[i*8+0] += e*lo_bf(u.x); out[i*8+1] += e*hi_bf(u.x);
      out[i*8+2] += e*lo_bf(u.y); out[i*8+3] += e*hi_bf(u.y);
      out[i*8+4] += e*lo_bf(u.z); out[i*8+5] += e*hi_bf(u.z);
      out[i*8+6] += e*lo_bf(u.w); out[i*8+7] += e*hi_bf(u.w);
    }
  }
  denP[((size_t)h*NCHUNK + c)*NLAND + t] = den;
  float* np = numP + (((size_t)h*NCHUNK + c)*NLAND + t)*DHEAD;
  #pragma unroll
  for(int i=0;i<16;i++){
    float4 v = make_float4(out[i*4], out[i*4+1], out[i*4+2], out[i*4+3]);
    *(float4*)(np + i*4) = v;
  }
}

__global__ void k_a3v_comb(const float* __restrict__ numP, const float* __restrict__ denP,
                           float* __restrict__ a3v){
  int bidx = blockIdx.x;           // h*256 + m
  int h = bidx >> 8, m = bidx & 255;
  int d = threadIdx.x;
  float s = 0.f, den = 0.f;
  for(int c=0;c<NCHUNK;c++){
    s += numP[(((size_t)h*NCHUNK + c)*NLAND + m)*DHEAD + d];
    den += denP[((size_t)h*NCHUNK + c)*NLAND + m];
  }
  a3v[((size_t)h*NLAND + m)*DHEAD + d] = s / den;
}

// ---------------- a1: per-thread-row, softmax(q@kl^T)@w2 -> F ----------------
// grid (row-block, head). 256 threads = 256 q rows each.
__global__ __launch_bounds__(256) void k_a1(const float* __restrict__ Qb,
    const float* __restrict__ kl, const float* __restrict__ w2, float* __restrict__ F){
  __shared__ unsigned klL[256*32];
  __shared__ unsigned w2L[256*32];
  int h = blockIdx.y, t = threadIdx.x;
  const float* klh = kl + (size_t)h*NLAND*DHEAD;
  const float* w2h = w2 + (size_t)h*NLAND*DHEAD;
  #pragma unroll
  for(int i=0;i<16;i++){
    int fi = i*256 + t;
    float4 a = *(const float4*)(klh + (size_t)fi*4);
    float4 b = *(const float4*)(w2h + (size_t)fi*4);
    klL[fi*2]   = packbf(a.x,a.y); klL[fi*2+1] = packbf(a.z,a.w);
    w2L[fi*2]   = packbf(b.x,b.y); w2L[fi*2+1] = packbf(b.z,b.w);
  }
  __syncthreads();
  int row = blockIdx.x*256 + t;
  const float* qp = Qb + ((size_t)h*NPAD + row)*DHEAD;
  float q[64];
  #pragma unroll
  for(int i=0;i<16;i++){
    float4 v = *(const float4*)(qp + i*4);
    q[i*4]=v.x; q[i*4+1]=v.y; q[i*4+2]=v.z; q[i*4+3]=v.w;
  }
  float out[64];
  #pragma unroll
  for(int i=0;i<64;i++) out[i] = 0.f;
  float den = 0.f;
  for(int m=0;m<256;m++){
    const uint4* kr = (const uint4*)&klL[m*32];
    float s0=0,s1=0,s2=0,s3=0;
    #pragma unroll
    for(int i=0;i<8;i++){
      uint4 u = kr[i];
      s0 += q[i*8+0]*lo_bf(u.x) + q[i*8+1]*hi_bf(u.x);
      s1 += q[i*8+2]*lo_bf(u.y) + q[i*8+3]*hi_bf(u.y);
      s2 += q[i*8+4]*lo_bf(u.z) + q[i*8+5]*hi_bf(u.z);
      s3 += q[i*8+6]*lo_bf(u.w) + q[i*8+7]*hi_bf(u.w);
    }
    float e = __expf((s0+s1)+(s2+s3));
    den += e;
    const uint4* wr = (const uint4*)&w2L[m*32];
    #pragma unroll
    for(int i=0;i<8;i++){
      uint4 u = wr[i];
      out[i*8+0] += e*lo_bf(u.x); out[i*8+1] += e*hi_bf(u.x);
      out[i*8+2] += e*lo_bf(u.y); out[i*8+3] += e*hi_bf(u.y);
      out[i*8+4] += e*lo_bf(u.z); out[i*8+5] += e*hi_bf(u.z);
      out[i*8+6] += e*lo_bf(u.w); out[i*8+7] += e*hi_bf(u.w);
    }
  }
  float inv = 1.f/den;
  float* op = F + (size_t)row*CDIM + h*DHEAD;
  #pragma unroll
  for(int i=0;i<16;i++){
    float4 v = make_float4(out[i*4]*inv, out[i*4+1]*inv, out[i*4+2]*inv, out[i*4+3]*inv);
    *(float4*)(op + i*4) = v;
  }
}

// ---------------- residual depthwise conv along sequence (k=33) ----------------
__global__ void k_resconv(const float* __restrict__ Vb, const float* __restrict__ rw,
                          float* __restrict__ F){
  int n = blockIdx.x;
  int c = blockIdx.y*256 + threadIdx.x;
  int h = c >> 6, d = c & 63;
  const float* vh = Vb + (size_t)h*NPAD*DHEAD + d;
  float s = 0.f;
  #pragma unroll
  for(int j=0;j<33;j++){
    int nn = n + j - 16;
    if(nn >= 0 && nn < NPAD) s += rw[h*33 + j] * vh[(size_t)nn*DHEAD];
  }
  F[(size_t)n*CDIM + c] += s;
}

// ---------------- transpose ----------------
__global__ void k_transpose(const float* __restrict__ in, float* __restrict__ out,
                            int R, int C){
  __shared__ float tile[32][33];
  int r0 = blockIdx.x*32, c0 = blockIdx.y*32;
  int tx = threadIdx.x, ty = threadIdx.y;
  #pragma unroll
  for(int r=0;r<4;r++) tile[ty + r*8][tx] = in[(size_t)(r0 + ty + r*8)*C + c0 + tx];
  __syncthreads();
  #pragma unroll
  for(int r=0;r<4;r++) out[(size_t)(c0 + ty + r*8)*R + r0 + tx] = tile[tx][ty + r*8];
}

// ---------------- PPEG depthwise 7/5/3 conv ----------------
__global__ __launch_bounds__(256) void k_ppeg(const float* __restrict__ img,
    const float* __restrict__ w7, const float* __restrict__ b7,
    const float* __restrict__ w5, const float* __restrict__ b5,
    const float* __restrict__ w3, const float* __restrict__ b3,
    float* __restrict__ out){
  __shared__ float patch[22*22];
  __shared__ float wbuf[83];
  int c = blockIdx.y;
  int tj = blockIdx.x & 7, ti = blockIdx.x >> 3;
  int t = threadIdx.x;
  const float* im = img + (size_t)c*16384;
  int i0 = ti*16 - 3, j0 = tj*16 - 3;
  for(int idx = t; idx < 484; idx += 256){
    int pi = idx / 22, pj = idx % 22;
    int gi = i0 + pi, gj = j0 + pj;
    patch[idx] = (gi>=0 && gi<128 && gj>=0 && gj<128) ? im[gi*128 + gj] : 0.f;
  }
  if(t < 49) wbuf[t] = w7[c*49 + t];
  else if(t < 74) wbuf[t] = w5[c*25 + (t-49)];
  else if(t < 83) wbuf[t] = w3[c*9 + (t-74)];
  __syncthreads();
  int i = t >> 4, j = t & 15;
  float s = patch[(i+3)*22 + (j+3)];
  #pragma unroll
  for(int a=0;a<7;a++)
    #pragma unroll
    for(int bq=0;bq<7;bq++) s += wbuf[a*7+bq] * patch[(i+a)*22 + (j+bq)];
  s += b7[c];
  #pragma unroll
  for(int a=0;a<5;a++)
    #pragma unroll
    for(int bq=0;bq<5;bq++) s += wbuf[49+a*5+bq] * patch[(i+a+1)*22 + (j+bq+1)];
  s += b5[c];
  #pragma unroll
  for(int a=0;a<3;a++)
    #pragma unroll
    for(int bq=0;bq<3;bq++) s += wbuf[74+a*3+bq] * patch[(i+a+2)*22 + (j+bq+2)];
  s += b3[c];
  out[(size_t)c*16384 + (ti*16+i)*128 + (tj*16+j)] = s;
}

// ---------------- final LN(row0) + fc2 ----------------
__global__ __launch_bounds__(512) void k_final(const float* __restrict__ A,
    const float* __restrict__ g, const float* __restrict__ b,
    const float* __restrict__ w, const float* __restrict__ bias,
    float* __restrict__ outp){
  __shared__ float red[8];
  int t = threadIdx.x, wv = t >> 6;
  float x = A[t];
  float s = wave_sum(x);
  if((t & 63) == 0) red[wv] = s;
  __syncthreads();
  float mu = 0;
  #pragma unroll
  for(int i=0;i<8;i++) mu += red[i];
  mu *= (1.f/512.f);
  __syncthreads();
  float dx = x - mu;
  s = wave_sum(dx*dx);
  if((t & 63) == 0) red[wv] = s;
  __syncthreads();
  float var = 0;
  #pragma unroll
  for(int i=0;i<8;i++) var += red[i];
  var *= (1.f/512.f);
  float xn = dx * rsqrtf(var + 1e-5f) * g[t] + b[t];
  __syncthreads();
  for(int o=0;o<4;o++){
    s = wave_sum(xn * w[t*4 + o]);
    if((t & 63) == 0) red[wv] = s;
    __syncthreads();
    if(t == 0){
      float r = 0;
      #pragma unroll
      for(int i=0;i<8;i++) r += red[i];
      outp[o] = r + bias[o];
    }
    __syncthreads();
  }
}

extern "C" void kernel_launch(void* const* d_in, const int* in_sizes, int n_in,
                              void* d_out, int out_size, void* d_ws, size_t ws_size,
                              hipStream_t stream) {
  (void)in_sizes; (void)n_in; (void)out_size; (void)ws_size;
  const float* data_x = (const float*)d_in[0];
  const float* fc1_w  = (const float*)d_in[1];
  const float* fc1_b  = (const float*)d_in[2];
  const float* cls_tk = (const float*)d_in[3];
  const float* ng[2]  = {(const float*)d_in[4],  (const float*)d_in[16]};
  const float* nb[2]  = {(const float*)d_in[5],  (const float*)d_in[17]};
  const float* qkvw[2]= {(const float*)d_in[6],  (const float*)d_in[18]};
  const float* outw[2]= {(const float*)d_in[7],  (const float*)d_in[19]};
  const float* outb[2]= {(const float*)d_in[8],  (const float*)d_in[20]};
  const float* resw[2]= {(const float*)d_in[9],  (const float*)d_in[21]};
  const float* w7 = (const float*)d_in[10]; const float* pb7 = (const float*)d_in[11];
  const float* w5 = (const float*)d_in[12]; const float* pb5 = (const float*)d_in[13];
  const float* w3 = (const float*)d_in[14]; const float* pb3 = (const float*)d_in[15];
  const float* norm_g = (const float*)d_in[22];
  const float* norm_b = (const float*)d_in[23];
  const float* fc2_w  = (const float*)d_in[24];
  const float* fc2_b  = (const float*)d_in[25];

  float* ws = (float*)d_ws;
  float* Ab   = ws;                         // 16385*512
  float* Bb   = Ab + (size_t)TOK*CDIM;      // 16640*512
  float* Qb   = Bb + (size_t)NPAD*CDIM;
  float* Kb   = Qb + (size_t)NPAD*CDIM;
  float* Vb   = Kb + (size_t)NPAD*CDIM;
  float* Fb   = Vb + (size_t)NPAD*CDIM;     // pre-proj out; also a3v numP scratch
  float* qlb  = Fb + (size_t)NPAD*CDIM;     // 8*256*64
  float* klb  = qlb + NHEAD*NLAND*DHEAD;
  float* a2b  = klb + NHEAD*NLAND*DHEAD;    // 8*256*256
  float* z0b  = a2b + NHEAD*NLAND*NLAND;
  float* z1b  = z0b + NHEAD*NLAND*NLAND;
  float* Xb_  = z1b + NHEAD*NLAND*NLAND;
  float* Tb_  = Xb_ + NHEAD*NLAND*NLAND;
  float* Ub_  = Tb_ + NHEAD*NLAND*NLAND;
  float* a3vb = Ub_ + NHEAD*NLAND*NLAND;    // 8*256*64
  float* w2b  = a3vb + NHEAD*NLAND*DHEAD;
  float* denP = w2b + NHEAD*NLAND*DHEAD;    // 8*65*256
  float* hmax = denP + NHEAD*NCHUNK*NLAND;  // 8
  float* scal = hmax + 8;                   // 1

  k_set_cls<<<1, 512, 0, stream>>>(Ab, cls_tk);
  k_gemm<0><<<dim3(4, 128), 256, 0, stream>>>(data_x, 1024, fc1_w, 512, fc1_b,
                                              Ab + CDIM, nullptr, nullptr, 16384, 1024);
  for(int L=0; L<2; L++){
    k_ln_pad<<<NPAD/4, 256, 0, stream>>>(Ab, ng[L], nb[L], Bb);
    k_gemm<1><<<dim3(12, 130), 256, 0, stream>>>(Bb, CDIM, qkvw[L], 1536, nullptr,
                                                 Qb, Kb, Vb, NPAD, CDIM);
    k_landmark<<<NHEAD*NLAND, 64, 0, stream>>>(Qb, qlb);
    k_landmark<<<NHEAD*NLAND, 64, 0, stream>>>(Kb, klb);
    k_a2<<<dim3(4, NHEAD), 256, 0, stream>>>(qlb, klb, a2b);
    k_colmax<<<NHEAD, 256, 0, stream>>>(a2b, hmax);
    k_scal<<<1, 64, 0, stream>>>(hmax, scal);
    k_zinit<<<dim3(256, NHEAD), 256, 0, stream>>>(a2b, scal, z0b);
    float* zc = z0b; float* zn = z1b;
    for(int it=0; it<6; it++){
      k_sgemm<0><<<dim3(8,8,NHEAD), 256, 0, stream>>>(a2b, zc, Xb_, 256,256,256,
                                                      65536,65536,65536, 0.f);
      k_eIminus<<<NHEAD*65536/256, 256, 0, stream>>>(Xb_, Tb_, 7.f);
      k_sgemm<1><<<dim3(8,8,NHEAD), 256, 0, stream>>>(Xb_, Tb_, Ub_, 256,256,256,
                                                      65536,65536,65536, 15.f);
      k_sgemm<1><<<dim3(8,8,NHEAD), 256, 0, stream>>>(Xb_, Ub_, Tb_, 256,256,256,
                                                      65536,65536,65536, 13.f);
      k_sgemm<2><<<dim3(8,8,NHEAD), 256, 0, stream>>>(zc, Tb_, zn, 256,256,256,
                                                      65536,65536,65536, 0.25f);
      float* tmp = zc; zc = zn; zn = tmp;
    }
    k_a3v<<<dim3(NHEAD, NCHUNK), 256, 0, stream>>>(qlb, Kb, Vb, Fb, denP);
    k_a3v_comb<<<NHEAD*NLAND, 64, 0, stream>>>(Fb, denP, a3vb);
    k_sgemm<0><<<dim3(2,8,NHEAD), 256, 0, stream>>>(zc, a3vb, w2b, 256,64,256,
                                                    65536,16384,16384, 0.f);
    k_a1<<<dim3(65, NHEAD), 256, 0, stream>>>(Qb, klb, w2b, Fb);
    k_resconv<<<dim3(NPAD, 2), 256, 0, stream>>>(Vb, resw[L], Fb);
    k_gemm<2><<<dim3(4, 129), 256, 0, stream>>>(Fb + (size_t)PAD0*CDIM, CDIM,
                                                outw[L], CDIM, outb[L],
                                                Ab, nullptr, nullptr, TOK, CDIM);
    if(L == 0){
      k_transpose<<<dim3(512, 16), dim3(32,8), 0, stream>>>(Ab + CDIM, Bb, 16384, 512);
      k_ppeg<<<dim3(64, 512), 256, 0, stream>>>(Bb, w7, pb7, w5, pb5, w3, pb3, Qb);
      k_transpose<<<dim3(16, 512), dim3(32,8), 0, stream>>>(Qb, Ab + CDIM, 512, 16384);
    }
  }
  k_final<<<1, 512, 0, stream>>>(Ab, norm_g, norm_b, fc2_w, fc2_b, (float*)d_out);
}

// Round 3
// 1961.351 us; speedup vs baseline: 3.7178x; 2.0724x over previous
//
#include <hip/hip_runtime.h>
#include <hip/hip_bf16.h>

#define NPAD 16640
#define TOK  16385
#define CDIM 512
#define NHEAD 8
#define DHEAD 64
#define NLAND 256
#define LFAC  65
#define PAD0  255
#define NCHUNK 65   // chunks of 256 rows: 65*256 = 16640

typedef __attribute__((ext_vector_type(8))) short sh8;
typedef __attribute__((ext_vector_type(4))) float f4;

__device__ __forceinline__ float wave_sum(float v){
  #pragma unroll
  for(int o=32;o;o>>=1) v += __shfl_xor(v,o);
  return v;
}
__device__ __forceinline__ float wave_max(float v){
  #pragma unroll
  for(int o=32;o;o>>=1) v = fmaxf(v, __shfl_xor(v,o));
  return v;
}

// bf16 RNE pack helpers
__device__ __forceinline__ unsigned bfbits(float x){
  unsigned u = __float_as_uint(x);
  return (u + 0x7fffu + ((u >> 16) & 1u)) >> 16;
}
__device__ __forceinline__ sh8 pack8f(float4 a, float4 b){
  sh8 r;
  r[0]=(short)bfbits(a.x); r[1]=(short)bfbits(a.y); r[2]=(short)bfbits(a.z); r[3]=(short)bfbits(a.w);
  r[4]=(short)bfbits(b.x); r[5]=(short)bfbits(b.y); r[6]=(short)bfbits(b.z); r[7]=(short)bfbits(b.w);
  return r;
}
#define MFMA16(a,b,c) __builtin_amdgcn_mfma_f32_16x16x32_bf16(a,b,c,0,0,0)

// ---------------- cls token ----------------
__global__ void k_set_cls(float* A, const float* __restrict__ cls){
  int t = threadIdx.x;
  if(t < CDIM) A[t] = cls[t];
}

// ---------------- layernorm + front pad ----------------
__global__ __launch_bounds__(256) void k_ln_pad(const float* __restrict__ A,
    const float* __restrict__ g, const float* __restrict__ b, float* __restrict__ B){
  int w = threadIdx.x >> 6, lane = threadIdx.x & 63;
  int row = blockIdx.x*4 + w;
  float* out = B + (size_t)row*CDIM;
  if(row < PAD0){
    #pragma unroll
    for(int i=0;i<8;i++) out[lane + i*64] = 0.f;
    return;
  }
  const float* x = A + (size_t)(row-PAD0)*CDIM;
  int c0 = lane*4, c1 = 256 + lane*4;
  float4 v0 = *(const float4*)(x + c0);
  float4 v1 = *(const float4*)(x + c1);
  float xs[8] = {v0.x,v0.y,v0.z,v0.w,v1.x,v1.y,v1.z,v1.w};
  float s = 0;
  #pragma unroll
  for(int i=0;i<8;i++) s += xs[i];
  s = wave_sum(s);
  float mu = s * (1.f/512.f);
  float vs = 0;
  #pragma unroll
  for(int i=0;i<8;i++){ float d = xs[i]-mu; vs += d*d; }
  vs = wave_sum(vs) * (1.f/512.f);
  float rs = rsqrtf(vs + 1e-5f);
  float4 g0 = *(const float4*)(g + c0); float4 g1 = *(const float4*)(g + c1);
  float4 b0 = *(const float4*)(b + c0); float4 b1 = *(const float4*)(b + c1);
  float4 o0, o1;
  o0.x = (xs[0]-mu)*rs*g0.x + b0.x; o0.y = (xs[1]-mu)*rs*g0.y + b0.y;
  o0.z = (xs[2]-mu)*rs*g0.z + b0.z; o0.w = (xs[3]-mu)*rs*g0.w + b0.w;
  o1.x = (xs[4]-mu)*rs*g1.x + b1.x; o1.y = (xs[5]-mu)*rs*g1.y + b1.y;
  o1.z = (xs[6]-mu)*rs*g1.z + b1.z; o1.w = (xs[7]-mu)*rs*g1.w + b1.w;
  *(float4*)(out + c0) = o0;
  *(float4*)(out + c1) = o1;
}

// ---------------- MFMA GEMM: C[M,N] = A[M,K] @ WT[N,K]^T, bf16 inputs ----------------
// 128x128 tile, BK=32, 4 waves each 64x64.
// MODE 0: fc1 relu(acc+bias) ; MODE 1: qkv scatter head-major, q*0.125 ; MODE 2: proj += acc+bias
template<int MODE>
__global__ __launch_bounds__(256) void k_gemm_mfma(const float* __restrict__ A, int lda,
    const float* __restrict__ WT, int K, const float* __restrict__ bias,
    float* out0, float* out1, float* out2, int M){
  __shared__ short As[128*32];
  __shared__ short Bs[128*32];
  int t = threadIdx.x, lane = t & 63, wv = t >> 6, g = lane >> 4, l15 = lane & 15;
  int row0 = blockIdx.y*128, n0 = blockIdx.x*128;
  int wm = (wv>>1)*64, wn = (wv&1)*64;
  f4 acc[4][4] = {};
  for(int k0 = 0; k0 < K; k0 += 32){
    #pragma unroll
    for(int u=0; u<2; u++){
      int gi = t + u*256;               // 512 granules of 8 elems
      int m = gi >> 2, kb = (gi & 3) * 8;
      // A tile
      float4 va = make_float4(0,0,0,0), vb = make_float4(0,0,0,0);
      int gr = row0 + m;
      if(gr < M){
        va = *(const float4*)(A + (size_t)gr*lda + k0 + kb);
        vb = *(const float4*)(A + (size_t)gr*lda + k0 + kb + 4);
      }
      int swz = (((m&3) ^ ((m>>2)&3)) << 4);
      *(sh8*)((char*)As + m*64 + ((kb*2) ^ swz)) = pack8f(va, vb);
      // B tile from WT[n][k]
      float4 wa = *(const float4*)(WT + (size_t)(n0+m)*K + k0 + kb);
      float4 wb = *(const float4*)(WT + (size_t)(n0+m)*K + k0 + kb + 4);
      *(sh8*)((char*)Bs + m*64 + ((kb*2) ^ swz)) = pack8f(wa, wb);
    }
    __syncthreads();
    sh8 af[4], bf[4];
    #pragma unroll
    for(int mt=0; mt<4; mt++){
      int r = wm + mt*16 + l15;
      af[mt] = *(sh8*)((char*)As + r*64 + ((g*16) ^ (((r&3)^((r>>2)&3))<<4)));
    }
    #pragma unroll
    for(int nt=0; nt<4; nt++){
      int r = wn + nt*16 + l15;
      bf[nt] = *(sh8*)((char*)Bs + r*64 + ((g*16) ^ (((r&3)^((r>>2)&3))<<4)));
    }
    #pragma unroll
    for(int mt=0; mt<4; mt++)
      #pragma unroll
      for(int nt=0; nt<4; nt++)
        acc[mt][nt] = MFMA16(af[mt], bf[nt], acc[mt][nt]);
    __syncthreads();
  }
  #pragma unroll
  for(int mt=0; mt<4; mt++){
    #pragma unroll
    for(int r=0; r<4; r++){
      int gm = row0 + wm + mt*16 + g*4 + r;
      if(gm >= M) continue;
      #pragma unroll
      for(int nt=0; nt<4; nt++){
        int gn = n0 + wn + nt*16 + l15;
        float v = acc[mt][nt][r];
        if(MODE == 0){
          v += bias[gn];
          out0[(size_t)gm*CDIM + gn] = v > 0.f ? v : 0.f;
        } else if(MODE == 1){
          int p = gn >> 9, rr = gn & 511;
          int hh = rr >> 6, dd = rr & 63;
          if(p == 0) v *= 0.125f;
          float* dst = (p==0) ? out0 : (p==1 ? out1 : out2);
          dst[((size_t)hh*NPAD + gm)*DHEAD + dd] = v;
        } else {
          out0[(size_t)gm*CDIM + gn] += v + bias[gn];
        }
      }
    }
  }
}

// ---------------- landmark means ----------------
__global__ void k_landmark(const float* __restrict__ src, float* __restrict__ dst){
  int bidx = blockIdx.x;               // h*256 + m
  int h = bidx >> 8, m = bidx & 255, d = threadIdx.x;
  const float* p = src + ((size_t)h*NPAD + (size_t)m*LFAC)*DHEAD + d;
  float s = 0;
  for(int j=0;j<LFAC;j++) s += p[(size_t)j*DHEAD];
  dst[(size_t)bidx*DHEAD + d] = s * (1.f/LFAC);
}

// ---------------- a2 = softmax(ql @ kl^T) ----------------
__global__ __launch_bounds__(256) void k_a2(const float* __restrict__ ql,
    const float* __restrict__ kl, float* __restrict__ a2){
  __shared__ __hip_bfloat16 klt[64*256];  // [d][m]
  int h = blockIdx.y;
  int t = threadIdx.x;
  const float* klh = kl + (size_t)h*NLAND*DHEAD;
  for(int r=0;r<64;r++){
    int idx = r*256 + t;
    int d = idx >> 8, m = idx & 255;
    klt[idx] = __float2bfloat16(klh[m*DHEAD + d]);
  }
  __syncthreads();
  int w = t >> 6, lane = t & 63;
  const float* qlh = ql + (size_t)h*NLAND*DHEAD;
  for(int rr=0; rr<16; rr++){
    int m = blockIdx.x*64 + w*16 + rr;
    const float* q = qlh + (size_t)m*DHEAD;
    float s[4] = {0,0,0,0};
    #pragma unroll
    for(int d=0; d<64; d++){
      float qv = q[d];
      #pragma unroll
      for(int qd=0; qd<4; qd++)
        s[qd] += qv * __bfloat162float(klt[d*256 + qd*64 + lane]);
    }
    float e[4], den = 0.f;
    #pragma unroll
    for(int qd=0; qd<4; qd++){ e[qd] = __expf(s[qd]); den += e[qd]; }
    den = wave_sum(den);
    float inv = 1.f/den;
    float* arow = a2 + ((size_t)h*NLAND + m)*NLAND;
    #pragma unroll
    for(int qd=0; qd<4; qd++) arow[qd*64 + lane] = e[qd]*inv;
  }
}

// ---------------- pinv init ----------------
__global__ void k_colmax(const float* __restrict__ a2, float* __restrict__ hmax){
  __shared__ float red[4];
  int h = blockIdx.x, t = threadIdx.x;
  const float* p = a2 + (size_t)h*65536 + t;
  float s = 0;
  for(int m=0;m<256;m++) s += p[(size_t)m*256];
  float mx = wave_max(s);
  if((t & 63) == 0) red[t>>6] = mx;
  __syncthreads();
  if(t == 0) hmax[h] = fmaxf(fmaxf(red[0],red[1]), fmaxf(red[2],red[3]));
}
__global__ void k_scal(const float* __restrict__ hmax, float* __restrict__ scal){
  int t = threadIdx.x;
  float v = (t < 8) ? hmax[t] : -1e30f;
  v = wave_max(v);
  if(t == 0) scal[0] = v;
}
__global__ void k_zinit(const float* __restrict__ a2, const float* __restrict__ scal,
                        float* __restrict__ z){
  int h = blockIdx.y;
  int idx = blockIdx.x*256 + threadIdx.x;
  int m = idx >> 8, j = idx & 255;
  z[(size_t)h*65536 + idx] = a2[(size_t)h*65536 + (size_t)j*256 + m] / scal[0];
}

// ---------------- batched f32 GEMM 64x64 tile, 4x4/thread ----------------
// TRANS: B := alpha*I - B on load.  OUTT: write C transposed.  C = beta * (A@B')
template<int TRANS, int OUTT>
__global__ __launch_bounds__(256) void k_sgemm2(const float* __restrict__ A,
    const float* __restrict__ B, float* __restrict__ C,
    int M, int N, int K, long sA, long sB, long sC, float alpha, float beta){
  __shared__ float As[32][68];
  __shared__ float Bs[32][68];
  int bh = blockIdx.z;
  const float* Ah = A + (size_t)bh*sA;
  const float* Bh = B + (size_t)bh*sB;
  float* Ch = C + (size_t)bh*sC;
  int m0 = blockIdx.y*64, n0 = blockIdx.x*64;
  int t = threadIdx.x, tx = t & 15, ty = t >> 4;
  float acc[4][4] = {};
  for(int k0=0; k0<K; k0+=32){
    #pragma unroll
    for(int u=0; u<2; u++){
      int idx = t + u*256;
      int r = idx >> 3, cb = (idx & 7) * 4;        // A: row r (m), k-block
      float4 va = *(const float4*)(Ah + (size_t)(m0+r)*K + k0 + cb);
      As[cb+0][r]=va.x; As[cb+1][r]=va.y; As[cb+2][r]=va.z; As[cb+3][r]=va.w;
      int kr = idx >> 4, nb = (idx & 15) * 4;      // B: row k, col n
      float4 w = *(const float4*)(Bh + (size_t)(k0+kr)*N + n0 + nb);
      if(TRANS){
        int gk = k0 + kr;
        w.x = ((gk==n0+nb+0)?alpha:0.f) - w.x;
        w.y = ((gk==n0+nb+1)?alpha:0.f) - w.y;
        w.z = ((gk==n0+nb+2)?alpha:0.f) - w.z;
        w.w = ((gk==n0+nb+3)?alpha:0.f) - w.w;
      }
      *(float4*)&Bs[kr][nb] = w;
    }
    __syncthreads();
    #pragma unroll
    for(int k=0;k<32;k++){
      float a[4], b[4];
      *(float4*)a = *(const float4*)&As[k][ty*4];
      *(float4*)b = *(const float4*)&Bs[k][tx*4];
      #pragma unroll
      for(int i=0;i<4;i++)
        #pragma unroll
        for(int j=0;j<4;j++) acc[i][j] += a[i]*b[j];
    }
    __syncthreads();
  }
  #pragma unroll
  for(int i=0;i<4;i++){
    #pragma unroll
    for(int j=0;j<4;j++){
      int gm = m0 + ty*4 + i, gn = n0 + tx*4 + j;
      float v = acc[i][j] * beta;
      if(OUTT) Ch[(size_t)gn*M + gm] = v;
      else     Ch[(size_t)gm*N + gn] = v;
    }
  }
}

// ---------------- MFMA flash a1: F[:, h*64:] = softmax(Q @ kl^T) @ w2 ----------------
// block: 128 q-rows, 4 waves x 32 rows (2 subtiles of 16). m processed in 2 halves of 128.
__global__ __launch_bounds__(256) void k_a1_mfma(const float* __restrict__ Qb,
    const float* __restrict__ kl, const float* __restrict__ w2t, float* __restrict__ F){
  __shared__ short klL[128*64];    // [m][d] bf16, swizzled
  __shared__ short w2L[64*128];    // [d][m-half] bf16, swizzled
  __shared__ short pL[4][16*128];  // per-wave P buffer [n][m-half]
  int h = blockIdx.y, n0 = blockIdx.x*128;
  int t = threadIdx.x, lane = t & 63, wv = t >> 6, g = lane >> 4, l15 = lane & 15;
  const float* klh = kl + (size_t)h*NLAND*DHEAD;
  const float* w2h = w2t + (size_t)h*DHEAD*NLAND;   // [64][256]
  const float* qbase = Qb + (size_t)h*NPAD*DHEAD;
  sh8 aQ[2][2];
  #pragma unroll
  for(int st=0; st<2; st++)
    #pragma unroll
    for(int kk=0; kk<2; kk++){
      const float* p = qbase + (size_t)(n0 + wv*32 + st*16 + l15)*DHEAD + kk*32 + g*8;
      aQ[st][kk] = pack8f(*(const float4*)p, *(const float4*)(p+4));
    }
  f4 accO[2][4] = {};
  float den[2][4] = {};
  short* pw = pL[wv];
  for(int half=0; half<2; half++){
    __syncthreads();
    #pragma unroll
    for(int it=0; it<4; it++){
      int gi = t + it*256;                  // 1024 granules
      int m = gi >> 3, db = (gi & 7) * 8;   // klL
      const float* p = klh + (size_t)(half*128 + m)*DHEAD + db;
      *(sh8*)((char*)klL + m*128 + ((db*2) ^ ((m&7)<<4))) =
          pack8f(*(const float4*)p, *(const float4*)(p+4));
      int d = gi >> 4, mb = (gi & 15) * 8;  // w2L
      const float* p2 = w2h + (size_t)d*NLAND + half*128 + mb;
      *(sh8*)((char*)w2L + d*256 + ((mb*2) ^ ((d&7)<<4))) =
          pack8f(*(const float4*)p2, *(const float4*)(p2+4));
    }
    __syncthreads();
    #pragma unroll
    for(int st=0; st<2; st++){
      #pragma unroll
      for(int mt=0; mt<8; mt++){
        f4 s = {};
        #pragma unroll
        for(int kk=0; kk<2; kk++){
          int m = mt*16 + l15;
          sh8 b = *(sh8*)((char*)klL + m*128 + ((kk*64 + g*16) ^ ((m&7)<<4)));
          s = MFMA16(aQ[st][kk], b, s);
        }
        #pragma unroll
        for(int r=0; r<4; r++){
          float e = __expf(s[r]);
          den[st][r] += e;
          int n = g*4 + r;
          *(short*)((char*)pw + n*256 + (((mt*16+l15)*2) ^ ((n&7)<<4))) = (short)bfbits(e);
        }
      }
      __syncthreads();
      #pragma unroll
      for(int ks=0; ks<4; ks++){
        sh8 aP = *(sh8*)((char*)pw + l15*256 + ((ks*64 + g*16) ^ ((l15&7)<<4)));
        #pragma unroll
        for(int dt=0; dt<4; dt++){
          int d = dt*16 + l15;
          sh8 bW = *(sh8*)((char*)w2L + d*256 + ((ks*64 + g*16) ^ ((d&7)<<4)));
          accO[st][dt] = MFMA16(aP, bW, accO[st][dt]);
        }
      }
      __syncthreads();
    }
  }
  #pragma unroll
  for(int st=0; st<2; st++)
    #pragma unroll
    for(int r=0; r<4; r++){
      float d_ = den[st][r];
      d_ += __shfl_xor(d_,1); d_ += __shfl_xor(d_,2);
      d_ += __shfl_xor(d_,4); d_ += __shfl_xor(d_,8);
      den[st][r] = 1.f/d_;
    }
  #pragma unroll
  for(int st=0; st<2; st++)
    #pragma unroll
    for(int dt=0; dt<4; dt++)
      #pragma unroll
      for(int r=0; r<4; r++){
        int row = n0 + wv*32 + st*16 + g*4 + r;
        F[(size_t)row*CDIM + h*DHEAD + dt*16 + l15] = accO[st][dt][r]*den[st][r];
      }
}

// ---------------- MFMA flash a3v: partial softmax(ql @ K^T) @ V over 256-col chunks ----------------
__global__ __launch_bounds__(256) void k_a3v_mfma(const float* __restrict__ ql,
    const float* __restrict__ Kb, const float* __restrict__ Vb,
    float* __restrict__ numP, float* __restrict__ denP){
  __shared__ short kL[128*64];
  __shared__ short vL[64*128];
  __shared__ short pL[4][16*128];
  int h = blockIdx.x, c = blockIdx.y;
  int t = threadIdx.x, lane = t & 63, wv = t >> 6, g = lane >> 4, l15 = lane & 15;
  const float* qlh = ql + (size_t)h*NLAND*DHEAD;
  sh8 aQ[4][2];
  #pragma unroll
  for(int st=0; st<4; st++)
    #pragma unroll
    for(int kk=0; kk<2; kk++){
      const float* p = qlh + (size_t)(wv*64 + st*16 + l15)*DHEAD + kk*32 + g*8;
      aQ[st][kk] = pack8f(*(const float4*)p, *(const float4*)(p+4));
    }
  f4 accO[4][4] = {};
  float den[4][4] = {};
  short* pw = pL[wv];
  for(int half=0; half<2; half++){
    const float* Kh = Kb + ((size_t)h*NPAD + (size_t)c*256 + half*128)*DHEAD;
    const float* Vh = Vb + ((size_t)h*NPAD + (size_t)c*256 + half*128)*DHEAD;
    __syncthreads();
    #pragma unroll
    for(int it=0; it<4; it++){
      int gi = t + it*256;
      int m = gi >> 3, db = (gi & 7) * 8;
      const float* p = Kh + (size_t)m*DHEAD + db;
      *(sh8*)((char*)kL + m*128 + ((db*2) ^ ((m&7)<<4))) =
          pack8f(*(const float4*)p, *(const float4*)(p+4));
    }
    #pragma unroll
    for(int it=0; it<8; it++){
      int idx = t + it*256;                 // 2048 float4 units
      int m = idx & 127, d0 = (idx >> 7) * 4;
      float4 v = *(const float4*)(Vh + (size_t)m*DHEAD + d0);
      float vv[4] = {v.x, v.y, v.z, v.w};
      #pragma unroll
      for(int i=0;i<4;i++){
        int d = d0 + i;
        *(short*)((char*)vL + d*256 + ((m*2) ^ ((d&7)<<4))) = (short)bfbits(vv[i]);
      }
    }
    __syncthreads();
    #pragma unroll
    for(int st=0; st<4; st++){
      #pragma unroll
      for(int mt=0; mt<8; mt++){
        f4 s = {};
        #pragma unroll
        for(int kk=0; kk<2; kk++){
          int m = mt*16 + l15;
          sh8 b = *(sh8*)((char*)kL + m*128 + ((kk*64 + g*16) ^ ((m&7)<<4)));
          s = MFMA16(aQ[st][kk], b, s);
        }
        #pragma unroll
        for(int r=0; r<4; r++){
          float e = __expf(s[r]);
          den[st][r] += e;
          int n = g*4 + r;
          *(short*)((char*)pw + n*256 + (((mt*16+l15)*2) ^ ((n&7)<<4))) = (short)bfbits(e);
        }
      }
      __syncthreads();
      #pragma unroll
      for(int ks=0; ks<4; ks++){
        sh8 aP = *(sh8*)((char*)pw + l15*256 + ((ks*64 + g*16) ^ ((l15&7)<<4)));
        #pragma unroll
        for(int dt=0; dt<4; dt++){
          int d = dt*16 + l15;
          sh8 bV = *(sh8*)((char*)vL + d*256 + ((ks*64 + g*16) ^ ((d&7)<<4)));
          accO[st][dt] = MFMA16(aP, bV, accO[st][dt]);
        }
      }
      __syncthreads();
    }
  }
  #pragma unroll
  for(int st=0; st<4; st++)
    #pragma unroll
    for(int r=0; r<4; r++){
      float d_ = den[st][r];
      d_ += __shfl_xor(d_,1); d_ += __shfl_xor(d_,2);
      d_ += __shfl_xor(d_,4); d_ += __shfl_xor(d_,8);
      den[st][r] = d_;
    }
  size_t base = ((size_t)h*NCHUNK + c)*NLAND;
  #pragma unroll
  for(int st=0; st<4; st++){
    #pragma unroll
    for(int r=0; r<4; r++){
      int row = wv*64 + st*16 + g*4 + r;
      if(l15 == 0) denP[base + row] = den[st][r];
      #pragma unroll
      for(int dt=0; dt<4; dt++)
        numP[(base + row)*DHEAD + dt*16 + l15] = accO[st][dt][r];
    }
  }
}

__global__ void k_a3v_comb(const float* __restrict__ numP, const float* __restrict__ denP,
                           float* __restrict__ a3v){
  int bidx = blockIdx.x;           // h*256 + m
  int h = bidx >> 8, m = bidx & 255;
  int d = threadIdx.x;
  float s = 0.f, den = 0.f;
  for(int c=0;c<NCHUNK;c++){
    s += numP[(((size_t)h*NCHUNK + c)*NLAND + m)*DHEAD + d];
    den += denP[((size_t)h*NCHUNK + c)*NLAND + m];
  }
  a3v[((size_t)h*NLAND + m)*DHEAD + d] = s / den;
}

// ---------------- residual depthwise conv along sequence (k=33) ----------------
__global__ void k_resconv(const float* __restrict__ Vb, const float* __restrict__ rw,
                          float* __restrict__ F){
  int n = blockIdx.x;
  int c = blockIdx.y*256 + threadIdx.x;
  int h = c >> 6, d = c & 63;
  const float* vh = Vb + (size_t)h*NPAD*DHEAD + d;
  float s = 0.f;
  #pragma unroll
  for(int j=0;j<33;j++){
    int nn = n + j - 16;
    if(nn >= 0 && nn < NPAD) s += rw[h*33 + j] * vh[(size_t)nn*DHEAD];
  }
  F[(size_t)n*CDIM + c] += s;
}

// ---------------- transpose ----------------
__global__ void k_transpose(const float* __restrict__ in, float* __restrict__ out,
                            int R, int C){
  __shared__ float tile[32][33];
  int r0 = blockIdx.x*32, c0 = blockIdx.y*32;
  int tx = threadIdx.x, ty = threadIdx.y;
  #pragma unroll
  for(int r=0;r<4;r++) tile[ty + r*8][tx] = in[(size_t)(r0 + ty + r*8)*C + c0 + tx];
  __syncthreads();
  #pragma unroll
  for(int r=0;r<4;r++) out[(size_t)(c0 + ty + r*8)*R + r0 + tx] = tile[tx][ty + r*8];
}

// ---------------- PPEG depthwise 7/5/3 conv ----------------
__global__ __launch_bounds__(256) void k_ppeg(const float* __restrict__ img,
    const float* __restrict__ w7, const float* __restrict__ b7,
    const float* __restrict__ w5, const float* __restrict__ b5,
    const float* __restrict__ w3, const float* __restrict__ b3,
    float* __restrict__ out){
  __shared__ float patch[22*22];
  __shared__ float wbuf[83];
  int c = blockIdx.y;
  int tj = blockIdx.x & 7, ti = blockIdx.x >> 3;
  int t = threadIdx.x;
  const float* im = img + (size_t)c*16384;
  int i0 = ti*16 - 3, j0 = tj*16 - 3;
  for(int idx = t; idx < 484; idx += 256){
    int pi = idx / 22, pj = idx % 22;
    int gi = i0 + pi, gj = j0 + pj;
    patch[idx] = (gi>=0 && gi<128 && gj>=0 && gj<128) ? im[gi*128 + gj] : 0.f;
  }
  if(t < 49) wbuf[t] = w7[c*49 + t];
  else if(t < 74) wbuf[t] = w5[c*25 + (t-49)];
  else if(t < 83) wbuf[t] = w3[c*9 + (t-74)];
  __syncthreads();
  int i = t >> 4, j = t & 15;
  float s = patch[(i+3)*22 + (j+3)];
  #pragma unroll
  for(int a=0;a<7;a++)
    #pragma unroll
    for(int bq=0;bq<7;bq++) s += wbuf[a*7+bq] * patch[(i+a)*22 + (j+bq)];
  s += b7[c];
  #pragma unroll
  for(int a=0;a<5;a++)
    #pragma unroll
    for(int bq=0;bq<5;bq++) s += wbuf[49+a*5+bq] * patch[(i+a+1)*22 + (j+bq+1)];
  s += b5[c];
  #pragma unroll
  for(int a=0;a<3;a++)
    #pragma unroll
    for(int bq=0;bq<3;bq++) s += wbuf[74+a*3+bq] * patch[(i+a+2)*22 + (j+bq+2)];
  s += b3[c];
  out[(size_t)c*16384 + (ti*16+i)*128 + (tj*16+j)] = s;
}

// ---------------- final LN(row0) + fc2 ----------------
__global__ __launch_bounds__(512) void k_final(const float* __restrict__ A,
    const float* __restrict__ g, const float* __restrict__ b,
    const float* __restrict__ w, const float* __restrict__ bias,
    float* __restrict__ outp){
  __shared__ float red[8];
  int t = threadIdx.x, wv = t >> 6;
  float x = A[t];
  float s = wave_sum(x);
  if((t & 63) == 0) red[wv] = s;
  __syncthreads();
  float mu = 0;
  #pragma unroll
  for(int i=0;i<8;i++) mu += red[i];
  mu *= (1.f/512.f);
  __syncthreads();
  float dx = x - mu;
  s = wave_sum(dx*dx);
  if((t & 63) == 0) red[wv] = s;
  __syncthreads();
  float var = 0;
  #pragma unroll
  for(int i=0;i<8;i++) var += red[i];
  var *= (1.f/512.f);
  float xn = dx * rsqrtf(var + 1e-5f) * g[t] + b[t];
  __syncthreads();
  for(int o=0;o<4;o++){
    s = wave_sum(xn * w[t*4 + o]);
    if((t & 63) == 0) red[wv] = s;
    __syncthreads();
    if(t == 0){
      float r = 0;
      #pragma unroll
      for(int i=0;i<8;i++) r += red[i];
      outp[o] = r + bias[o];
    }
    __syncthreads();
  }
}

extern "C" void kernel_launch(void* const* d_in, const int* in_sizes, int n_in,
                              void* d_out, int out_size, void* d_ws, size_t ws_size,
                              hipStream_t stream) {
  (void)in_sizes; (void)n_in; (void)out_size; (void)ws_size;
  const float* data_x = (const float*)d_in[0];
  const float* fc1_w  = (const float*)d_in[1];
  const float* fc1_b  = (const float*)d_in[2];
  const float* cls_tk = (const float*)d_in[3];
  const float* ng[2]  = {(const float*)d_in[4],  (const float*)d_in[16]};
  const float* nb[2]  = {(const float*)d_in[5],  (const float*)d_in[17]};
  const float* qkvw[2]= {(const float*)d_in[6],  (const float*)d_in[18]};
  const float* outw[2]= {(const float*)d_in[7],  (const float*)d_in[19]};
  const float* outb[2]= {(const float*)d_in[8],  (const float*)d_in[20]};
  const float* resw[2]= {(const float*)d_in[9],  (const float*)d_in[21]};
  const float* w7 = (const float*)d_in[10]; const float* pb7 = (const float*)d_in[11];
  const float* w5 = (const float*)d_in[12]; const float* pb5 = (const float*)d_in[13];
  const float* w3 = (const float*)d_in[14]; const float* pb3 = (const float*)d_in[15];
  const float* norm_g = (const float*)d_in[22];
  const float* norm_b = (const float*)d_in[23];
  const float* fc2_w  = (const float*)d_in[24];
  const float* fc2_b  = (const float*)d_in[25];

  float* ws = (float*)d_ws;
  float* Ab   = ws;                         // 16385*512
  float* Bb   = Ab + (size_t)TOK*CDIM;      // 16640*512
  float* Qb   = Bb + (size_t)NPAD*CDIM;
  float* Kb   = Qb + (size_t)NPAD*CDIM;
  float* Vb   = Kb + (size_t)NPAD*CDIM;
  float* Fb   = Vb + (size_t)NPAD*CDIM;     // pre-proj out; also a3v numP scratch
  float* qlb  = Fb + (size_t)NPAD*CDIM;     // 8*256*64
  float* klb  = qlb + NHEAD*NLAND*DHEAD;
  float* a2b  = klb + NHEAD*NLAND*DHEAD;    // 8*256*256
  float* z0b  = a2b + NHEAD*NLAND*NLAND;
  float* z1b  = z0b + NHEAD*NLAND*NLAND;
  float* Xb_  = z1b + NHEAD*NLAND*NLAND;
  float* Tb_  = Xb_ + NHEAD*NLAND*NLAND;
  float* Ub_  = Tb_ + NHEAD*NLAND*NLAND;
  float* a3vb = Ub_ + NHEAD*NLAND*NLAND;    // 8*256*64
  float* w2tb = a3vb + NHEAD*NLAND*DHEAD;   // 8*64*256 (transposed w2)
  float* denP = w2tb + NHEAD*DHEAD*NLAND;   // 8*65*256
  float* hmax = denP + NHEAD*NCHUNK*NLAND;  // 8
  float* scal = hmax + 8;                   // 1
  float* fc1T = scal + 8;                   // 512*1024
  float* qkvT0= fc1T + 512*1024;            // 1536*512
  float* qkvT1= qkvT0 + 1536*512;
  float* outT0= qkvT1 + 1536*512;           // 512*512
  float* outT1= outT0 + 512*512;
  float* qkvT[2] = {qkvT0, qkvT1};
  float* outT[2] = {outT0, outT1};

  // weight transposes (WT[n][k])
  k_transpose<<<dim3(32,16), dim3(32,8), 0, stream>>>(fc1_w, fc1T, 1024, 512);
  k_transpose<<<dim3(16,48), dim3(32,8), 0, stream>>>(qkvw[0], qkvT0, 512, 1536);
  k_transpose<<<dim3(16,48), dim3(32,8), 0, stream>>>(qkvw[1], qkvT1, 512, 1536);
  k_transpose<<<dim3(16,16), dim3(32,8), 0, stream>>>(outw[0], outT0, 512, 512);
  k_transpose<<<dim3(16,16), dim3(32,8), 0, stream>>>(outw[1], outT1, 512, 512);

  k_set_cls<<<1, 512, 0, stream>>>(Ab, cls_tk);
  k_gemm_mfma<0><<<dim3(4, 128), 256, 0, stream>>>(data_x, 1024, fc1T, 1024, fc1_b,
                                                   Ab + CDIM, nullptr, nullptr, 16384);
  for(int L=0; L<2; L++){
    k_ln_pad<<<NPAD/4, 256, 0, stream>>>(Ab, ng[L], nb[L], Bb);
    k_gemm_mfma<1><<<dim3(12, 130), 256, 0, stream>>>(Bb, CDIM, qkvT[L], CDIM, nullptr,
                                                      Qb, Kb, Vb, NPAD);
    k_landmark<<<NHEAD*NLAND, 64, 0, stream>>>(Qb, qlb);
    k_landmark<<<NHEAD*NLAND, 64, 0, stream>>>(Kb, klb);
    k_a2<<<dim3(4, NHEAD), 256, 0, stream>>>(qlb, klb, a2b);
    k_colmax<<<NHEAD, 256, 0, stream>>>(a2b, hmax);
    k_scal<<<1, 64, 0, stream>>>(hmax, scal);
    k_zinit<<<dim3(256, NHEAD), 256, 0, stream>>>(a2b, scal, z0b);
    float* zc = z0b; float* zn = z1b;
    for(int it=0; it<6; it++){
      // P = a2 @ z
      k_sgemm2<0,0><<<dim3(4,4,NHEAD), 256, 0, stream>>>(a2b, zc, Xb_, 256,256,256,
                                                         65536,65536,65536, 0.f, 1.f);
      // S2 = P @ (7I - P)
      k_sgemm2<1,0><<<dim3(4,4,NHEAD), 256, 0, stream>>>(Xb_, Xb_, Tb_, 256,256,256,
                                                         65536,65536,65536, 7.f, 1.f);
      // S4 = P @ (15I - S2)
      k_sgemm2<1,0><<<dim3(4,4,NHEAD), 256, 0, stream>>>(Xb_, Tb_, Ub_, 256,256,256,
                                                         65536,65536,65536, 15.f, 1.f);
      // z' = 0.25 * z @ (13I - S4)
      k_sgemm2<1,0><<<dim3(4,4,NHEAD), 256, 0, stream>>>(zc, Ub_, zn, 256,256,256,
                                                         65536,65536,65536, 13.f, 0.25f);
      float* tmp = zc; zc = zn; zn = tmp;
    }
    k_a3v_mfma<<<dim3(NHEAD, NCHUNK), 256, 0, stream>>>(qlb, Kb, Vb, Fb, denP);
    k_a3v_comb<<<NHEAD*NLAND, 64, 0, stream>>>(Fb, denP, a3vb);
    // w2t[h] = (zc @ a3v)^T  -> [64][256]
    k_sgemm2<0,1><<<dim3(1,4,NHEAD), 256, 0, stream>>>(zc, a3vb, w2tb, 256,64,256,
                                                       65536,16384,16384, 0.f, 1.f);
    k_a1_mfma<<<dim3(130, NHEAD), 256, 0, stream>>>(Qb, klb, w2tb, Fb);
    k_resconv<<<dim3(NPAD, 2), 256, 0, stream>>>(Vb, resw[L], Fb);
    k_gemm_mfma<2><<<dim3(4, 129), 256, 0, stream>>>(Fb + (size_t)PAD0*CDIM, CDIM,
                                                     outT[L], CDIM, outb[L],
                                                     Ab, nullptr, nullptr, TOK);
    if(L == 0){
      k_transpose<<<dim3(512, 16), dim3(32,8), 0, stream>>>(Ab + CDIM, Bb, 16384, 512);
      k_ppeg<<<dim3(64, 512), 256, 0, stream>>>(Bb, w7, pb7, w5, pb5, w3, pb3, Qb);
      k_transpose<<<dim3(16, 512), dim3(32,8), 0, stream>>>(Qb, Ab + CDIM, 512, 16384);
    }
  }
  k_final<<<1, 512, 0, stream>>>(Ab, norm_g, norm_b, fc2_w, fc2_b, (float*)d_out);
}